// Round 1
// baseline (82.754 us; speedup 1.0000x reference)
//
#include <hip/hip_runtime.h>
#include <cstdint>

#define NPTS 512
#define DIM 256
#define MARGIN_F 0.2f
#define FIX_SCALE 1099511627776.0  // 2^40

__device__ __forceinline__ uint32_t rotl32(uint32_t x, uint32_t r) {
  return (x << r) | (x >> (32u - r));
}

// JAX threefry2x32 with key (0, 42)  [jax.random.key(42) -> k1=0, k2=42],
// partitionable mode: bits = out0 ^ out1, counter x = (hi32(m)=0, lo32(m)=m).
__device__ __forceinline__ uint32_t threefry_bits(uint32_t c1) {
  const uint32_t k0 = 0u, k1 = 42u;
  const uint32_t k2 = k0 ^ k1 ^ 0x1BD11BDAu;
  uint32_t x0 = 0u + k0;
  uint32_t x1 = c1 + k1;
#define TFR(r) { x0 += x1; x1 = rotl32(x1, r); x1 ^= x0; }
  TFR(13u) TFR(15u) TFR(26u) TFR(6u)
  x0 += k1; x1 += k2 + 1u;
  TFR(17u) TFR(29u) TFR(16u) TFR(24u)
  x0 += k2; x1 += k0 + 2u;
  TFR(13u) TFR(15u) TFR(26u) TFR(6u)
  x0 += k0; x1 += k1 + 3u;
  TFR(17u) TFR(29u) TFR(16u) TFR(24u)
  x0 += k1; x1 += k2 + 4u;
  TFR(13u) TFR(15u) TFR(26u) TFR(6u)
  x0 += k2; x1 += k0 + 5u;
#undef TFR
  return x0 ^ x1;
}

// One block (256 threads = 4 waves) per anchor a.
__global__ __launch_bounds__(256) void triplet_main(
    const float* __restrict__ emb,
    const int* __restrict__ labels,
    unsigned long long* __restrict__ acc)  // acc[0] = fixed-point sum, acc[1] = count
{
  __shared__ float ea[DIM];
  __shared__ float dr[NPTS];
  __shared__ int lab[NPTS];

  const int a = blockIdx.x;
  const int t = threadIdx.x;

  ea[t] = emb[a * DIM + t];
  lab[t] = labels[t];
  lab[t + 256] = labels[t + 256];
  __syncthreads();

  // anchor squared norm (same value in every thread, deterministic order)
  float na = 0.f;
  #pragma unroll 8
  for (int d = 0; d < DIM; ++d) na += ea[d] * ea[d];

  // squared distances from anchor a to all j
  for (int j = t; j < NPTS; j += 256) {
    const float4* rj = reinterpret_cast<const float4*>(emb + j * DIM);
    const float4* wa = reinterpret_cast<const float4*>(ea);
    float s0 = 0, s1 = 0, s2 = 0, s3 = 0;
    float q0 = 0, q1 = 0, q2 = 0, q3 = 0;
    #pragma unroll 8
    for (int d4 = 0; d4 < DIM / 4; ++d4) {
      float4 v = rj[d4];
      float4 w = wa[d4];
      s0 += v.x * w.x; s1 += v.y * w.y; s2 += v.z * w.z; s3 += v.w * w.w;
      q0 += v.x * v.x; q1 += v.y * v.y; q2 += v.z * v.z; q3 += v.w * v.w;
    }
    float dot = (s0 + s1) + (s2 + s3);
    float nj  = (q0 + q1) + (q2 + q3);
    float sd = na + nj - 2.f * dot;
    dr[j] = sd > 0.f ? sd : 0.f;
  }
  __syncthreads();

  const int wave = t >> 6, lane = t & 63;
  const int la = lab[a];
  unsigned long long lsum = 0ull;
  unsigned long long lcnt = 0ull;

  // waves split the positive-candidate loop over p
  for (int p = wave; p < NPTS; p += 4) {
    if (p == a || lab[p] != la) continue;   // wave-uniform branch
    const float dap = dr[p];
    const float hi  = dap + MARGIN_F;
    const uint32_t base = ((uint32_t)a << 18) | ((uint32_t)p << 9);

    int bestKey = -1, bestJ = 0;
    for (int j = lane; j < NPTS; j += 64) {
      float dj = dr[j];
      if (lab[j] != la && dj > dap && dj < hi) {
        // 23-bit uniform key; argmax over gumbel == argmax over this key,
        // ties -> first (smallest) index, matching jnp.argmax.
        int key = (int)(threefry_bits(base + (uint32_t)j) >> 9);
        if (key > bestKey) { bestKey = key; bestJ = j; }
      }
    }
    // wave-wide reduce: max key, tie -> min index
    #pragma unroll
    for (int m = 32; m; m >>= 1) {
      int ok = __shfl_xor(bestKey, m);
      int oj = __shfl_xor(bestJ, m);
      if (ok > bestKey || (ok == bestKey && oj < bestJ)) { bestKey = ok; bestJ = oj; }
    }
    if (lane == 0 && bestKey >= 0) {
      float term = (dap - dr[bestJ]) + MARGIN_F;   // in (0, 0.2)
      lsum += (unsigned long long)((double)term * FIX_SCALE + 0.5);
      lcnt += 1ull;
    }
  }
  if (lane == 0 && lcnt) {
    atomicAdd(&acc[0], lsum);
    atomicAdd(&acc[1], lcnt);
  }
}

__global__ void triplet_finalize(const unsigned long long* __restrict__ acc,
                                 float* __restrict__ out)
{
  double s = (double)acc[0] / FIX_SCALE;
  double c = acc[1] ? (double)acc[1] : 1.0;
  out[0] = (float)(s / c);
}

extern "C" void kernel_launch(void* const* d_in, const int* in_sizes, int n_in,
                              void* d_out, int out_size, void* d_ws, size_t ws_size,
                              hipStream_t stream) {
  const float* emb   = (const float*)d_in[0];
  const int* labels  = (const int*)d_in[1];
  float* out         = (float*)d_out;
  unsigned long long* acc = (unsigned long long*)d_ws;

  hipMemsetAsync(d_ws, 0, 2 * sizeof(unsigned long long), stream);
  triplet_main<<<dim3(NPTS), dim3(256), 0, stream>>>(emb, labels, acc);
  triplet_finalize<<<dim3(1), dim3(1), 0, stream>>>(acc, out);
}

// Round 2
// 56.372 us; speedup vs baseline: 1.4680x; 1.4680x over previous
//
#include <hip/hip_runtime.h>
#include <cstdint>

#define NPTS 512
#define DIM 256
#define MARGIN_F 0.2f
#define FIX_SCALE 1099511627776.0  // 2^40

__device__ __forceinline__ uint32_t rotl32(uint32_t x, uint32_t r) {
  return (x << r) | (x >> (32u - r));
}

// JAX threefry2x32, key (0, 42), partitionable mode: bits = out0 ^ out1,
// counter x = (hi32(m)=0, lo32(m)=m). Verified bit-exact in round 1 (absmax 0).
__device__ __forceinline__ uint32_t threefry_bits(uint32_t c1) {
  const uint32_t k0 = 0u, k1 = 42u;
  const uint32_t k2 = k0 ^ k1 ^ 0x1BD11BDAu;
  uint32_t x0 = 0u + k0;
  uint32_t x1 = c1 + k1;
#define TFR(r) { x0 += x1; x1 = rotl32(x1, r); x1 ^= x0; }
  TFR(13u) TFR(15u) TFR(26u) TFR(6u)
  x0 += k1; x1 += k2 + 1u;
  TFR(17u) TFR(29u) TFR(16u) TFR(24u)
  x0 += k2; x1 += k0 + 2u;
  TFR(13u) TFR(15u) TFR(26u) TFR(6u)
  x0 += k0; x1 += k1 + 3u;
  TFR(17u) TFR(29u) TFR(16u) TFR(24u)
  x0 += k1; x1 += k2 + 4u;
  TFR(13u) TFR(15u) TFR(26u) TFR(6u)
  x0 += k2; x1 += k0 + 5u;
#undef TFR
  return x0 ^ x1;
}

// One block per 2 anchors. 512 threads = 8 waves.
__global__ __launch_bounds__(512) void triplet_main(
    const float* __restrict__ emb,
    const int* __restrict__ labels,
    unsigned long long* __restrict__ acc)  // acc[0]=fixed sum, acc[1]=count
{
  __shared__ float sea0[DIM];
  __shared__ float sea1[DIM];
  __shared__ float sd0[NPTS];   // dot(a0, j) -> then sqd(a0, j)
  __shared__ float sd1[NPTS];   // dot(a1, j) -> then sqd(a1, j)
  __shared__ float snrm[NPTS];  // ||j||^2
  __shared__ int   slab[NPTS];
  __shared__ int   plist[128];  // packed (ai<<16)|p positive pairs
  __shared__ int   pcnt;

  const int a0 = blockIdx.x * 2;
  const int a1 = a0 + 1;
  const int t = threadIdx.x;
  const int wave = t >> 6;
  const int lane = t & 63;
  const int grp = lane >> 4;    // 0..3  (16-lane group -> one j row)
  const int l16 = lane & 15;

  // ---- Phase 1: stage anchors + labels ----
  if (t < 256)       sea0[t]       = emb[a0 * DIM + t];
  else               sea1[t - 256] = emb[a1 * DIM + (t - 256)];
  slab[t] = labels[t];                      // t covers 0..511
  if (t == 0) pcnt = 0;
  __syncthreads();

  // ---- Phase 2: cooperative distances. Wave w owns j in [w*64, w*64+64).
  // 16-lane group per j; lanes split the 256-dim axis in float4 chunks.
  #pragma unroll 2
  for (int round = 0; round < 16; ++round) {
    const int j = (wave << 6) + (round << 2) + grp;
    float s0 = 0.f, s1 = 0.f, q = 0.f;
    #pragma unroll
    for (int it = 0; it < 4; ++it) {
      const int d = (it << 6) + (l16 << 2);
      const float4 v  = *reinterpret_cast<const float4*>(emb + j * DIM + d);
      const float4 w0 = *reinterpret_cast<const float4*>(sea0 + d);
      const float4 w1 = *reinterpret_cast<const float4*>(sea1 + d);
      s0 += v.x * w0.x + v.y * w0.y + v.z * w0.z + v.w * w0.w;
      s1 += v.x * w1.x + v.y * w1.y + v.z * w1.z + v.w * w1.w;
      q  += v.x * v.x  + v.y * v.y  + v.z * v.z  + v.w * v.w;
    }
    #pragma unroll
    for (int m = 8; m; m >>= 1) {
      s0 += __shfl_xor(s0, m);
      s1 += __shfl_xor(s1, m);
      q  += __shfl_xor(q, m);
    }
    if (l16 == 0) { sd0[j] = s0; sd1[j] = s1; snrm[j] = q; }
  }
  __syncthreads();

  // ---- Phase 2.5: dots -> squared distances; build positive-pair list ----
  {
    const float na0 = snrm[a0];
    const float na1 = snrm[a1];
    const float nj = snrm[t];
    const float v0 = na0 + nj - 2.f * sd0[t];
    const float v1 = na1 + nj - 2.f * sd1[t];
    __syncthreads();  // ensure all reads of sd before overwrite
    sd0[t] = v0 > 0.f ? v0 : 0.f;
    sd1[t] = v1 > 0.f ? v1 : 0.f;
    const int lp = slab[t];
    if (t != a0 && lp == slab[a0]) { int k = atomicAdd(&pcnt, 1); plist[k] = t; }
    if (t != a1 && lp == slab[a1]) { int k = atomicAdd(&pcnt, 1); plist[k] = (1 << 16) | t; }
  }
  __syncthreads();

  // ---- Phase 3: semi-hard scan + threefry argmax per positive pair ----
  unsigned long long lsum = 0ull, lcnt = 0ull;
  const int np = pcnt;
  for (int e = wave; e < np; e += 8) {
    const int ent = plist[e];
    const int ai = ent >> 16;
    const int p = ent & 0xffff;
    const float* drp = ai ? sd1 : sd0;
    const int ag = ai ? a1 : a0;
    const int la = slab[ag];
    const float dap = drp[p];
    const float hi = dap + MARGIN_F;
    const uint32_t base = ((uint32_t)ag << 18) | ((uint32_t)p << 9);

    int bestKey = -1, bestJ = 0;
    #pragma unroll
    for (int k = 0; k < 8; ++k) {
      const int j = lane + (k << 6);
      const float dj = drp[j];
      if (slab[j] != la && dj > dap && dj < hi) {
        const int key = (int)(threefry_bits(base + (uint32_t)j) >> 9);
        if (key > bestKey) { bestKey = key; bestJ = j; }
      }
    }
    #pragma unroll
    for (int m = 32; m; m >>= 1) {
      const int ok = __shfl_xor(bestKey, m);
      const int oj = __shfl_xor(bestJ, m);
      if (ok > bestKey || (ok == bestKey && oj < bestJ)) { bestKey = ok; bestJ = oj; }
    }
    if (lane == 0 && bestKey >= 0) {
      const float term = (dap - drp[bestJ]) + MARGIN_F;
      lsum += (unsigned long long)((double)term * FIX_SCALE + 0.5);
      lcnt += 1ull;
    }
  }
  if (lane == 0 && lcnt) {
    atomicAdd(&acc[0], lsum);
    atomicAdd(&acc[1], lcnt);
  }
}

__global__ void triplet_finalize(const unsigned long long* __restrict__ acc,
                                 float* __restrict__ out)
{
  double s = (double)acc[0] / FIX_SCALE;
  double c = acc[1] ? (double)acc[1] : 1.0;
  out[0] = (float)(s / c);
}

extern "C" void kernel_launch(void* const* d_in, const int* in_sizes, int n_in,
                              void* d_out, int out_size, void* d_ws, size_t ws_size,
                              hipStream_t stream) {
  const float* emb  = (const float*)d_in[0];
  const int* labels = (const int*)d_in[1];
  float* out        = (float*)d_out;
  unsigned long long* acc = (unsigned long long*)d_ws;

  hipMemsetAsync(d_ws, 0, 2 * sizeof(unsigned long long), stream);
  triplet_main<<<dim3(NPTS / 2), dim3(512), 0, stream>>>(emb, labels, acc);
  triplet_finalize<<<dim3(1), dim3(1), 0, stream>>>(acc, out);
}

// Round 3
// 20.482 us; speedup vs baseline: 4.0403x; 2.7523x over previous
//
#include <hip/hip_runtime.h>
#include <cstdint>

#define NPTS 512
#define DIM 256
#define NBLK (NPTS / 2)
#define MARGIN_F 0.2f
#define FIX_SCALE 1099511627776.0  // 2^40

__device__ __forceinline__ uint32_t rotl32(uint32_t x, uint32_t r) {
  return (x << r) | (x >> (32u - r));
}

// JAX threefry2x32, key (0, 42), partitionable mode: bits = out0 ^ out1,
// counter x = (hi32(m)=0, lo32(m)=m). Verified bit-exact (absmax 0.0, r1/r2).
__device__ __forceinline__ uint32_t threefry_bits(uint32_t c1) {
  const uint32_t k0 = 0u, k1 = 42u;
  const uint32_t k2 = k0 ^ k1 ^ 0x1BD11BDAu;
  uint32_t x0 = 0u + k0;
  uint32_t x1 = c1 + k1;
#define TFR(r) { x0 += x1; x1 = rotl32(x1, r); x1 ^= x0; }
  TFR(13u) TFR(15u) TFR(26u) TFR(6u)
  x0 += k1; x1 += k2 + 1u;
  TFR(17u) TFR(29u) TFR(16u) TFR(24u)
  x0 += k2; x1 += k0 + 2u;
  TFR(13u) TFR(15u) TFR(26u) TFR(6u)
  x0 += k0; x1 += k1 + 3u;
  TFR(17u) TFR(29u) TFR(16u) TFR(24u)
  x0 += k1; x1 += k2 + 4u;
  TFR(13u) TFR(15u) TFR(26u) TFR(6u)
  x0 += k2; x1 += k0 + 5u;
#undef TFR
  return x0 ^ x1;
}

// One block per 2 anchors. 512 threads = 8 waves. NO global atomics:
// each block writes a private (sum,count) slot; finalize reduces 256 slots.
__global__ __launch_bounds__(512) void triplet_main(
    const float* __restrict__ emb,
    const int* __restrict__ labels,
    unsigned long long* __restrict__ part)  // part[2b]=sum, part[2b+1]=cnt
{
  __shared__ float sea0[DIM];
  __shared__ float sea1[DIM];
  __shared__ float sd0[NPTS];   // dot(a0, j) -> then sqd(a0, j)
  __shared__ float sd1[NPTS];   // dot(a1, j) -> then sqd(a1, j)
  __shared__ float snrm[NPTS];  // ||j||^2
  __shared__ int   slab[NPTS];
  __shared__ int   plist[128];  // packed (ai<<16)|p positive pairs
  __shared__ int   pcnt;
  __shared__ unsigned long long wsum[8], wcnt[8];

  const int a0 = blockIdx.x * 2;
  const int a1 = a0 + 1;
  const int t = threadIdx.x;
  const int wave = t >> 6;
  const int lane = t & 63;
  const int grp = lane >> 4;    // 0..3  (16-lane group -> one j row)
  const int l16 = lane & 15;

  // ---- Phase 1: stage anchors + labels ----
  if (t < 256)       sea0[t]       = emb[a0 * DIM + t];
  else               sea1[t - 256] = emb[a1 * DIM + (t - 256)];
  slab[t] = labels[t];
  if (t == 0) pcnt = 0;
  __syncthreads();

  // ---- Phase 2: cooperative distances. Wave w owns j in [w*64, w*64+64).
  #pragma unroll 2
  for (int round = 0; round < 16; ++round) {
    const int j = (wave << 6) + (round << 2) + grp;
    float s0 = 0.f, s1 = 0.f, q = 0.f;
    #pragma unroll
    for (int it = 0; it < 4; ++it) {
      const int d = (it << 6) + (l16 << 2);
      const float4 v  = *reinterpret_cast<const float4*>(emb + j * DIM + d);
      const float4 w0 = *reinterpret_cast<const float4*>(sea0 + d);
      const float4 w1 = *reinterpret_cast<const float4*>(sea1 + d);
      s0 += v.x * w0.x + v.y * w0.y + v.z * w0.z + v.w * w0.w;
      s1 += v.x * w1.x + v.y * w1.y + v.z * w1.z + v.w * w1.w;
      q  += v.x * v.x  + v.y * v.y  + v.z * v.z  + v.w * v.w;
    }
    #pragma unroll
    for (int m = 8; m; m >>= 1) {
      s0 += __shfl_xor(s0, m);
      s1 += __shfl_xor(s1, m);
      q  += __shfl_xor(q, m);
    }
    if (l16 == 0) { sd0[j] = s0; sd1[j] = s1; snrm[j] = q; }
  }
  __syncthreads();

  // ---- Phase 2.5: dots -> squared distances; build positive-pair list ----
  {
    const float na0 = snrm[a0];
    const float na1 = snrm[a1];
    const float nj = snrm[t];
    const float v0 = na0 + nj - 2.f * sd0[t];
    const float v1 = na1 + nj - 2.f * sd1[t];
    __syncthreads();  // all reads of sd done before overwrite
    sd0[t] = v0 > 0.f ? v0 : 0.f;
    sd1[t] = v1 > 0.f ? v1 : 0.f;
    const int lp = slab[t];
    if (t != a0 && lp == slab[a0]) { int k = atomicAdd(&pcnt, 1); plist[k] = t; }
    if (t != a1 && lp == slab[a1]) { int k = atomicAdd(&pcnt, 1); plist[k] = (1 << 16) | t; }
  }
  __syncthreads();

  // ---- Phase 3: semi-hard scan + threefry argmax per positive pair ----
  unsigned long long lsum = 0ull, lcnt = 0ull;
  const int np = pcnt;
  for (int e = wave; e < np; e += 8) {
    const int ent = plist[e];
    const int ai = ent >> 16;
    const int p = ent & 0xffff;
    const float* drp = ai ? sd1 : sd0;
    const int ag = ai ? a1 : a0;
    const int la = slab[ag];
    const float dap = drp[p];
    const float hi = dap + MARGIN_F;
    const uint32_t base = ((uint32_t)ag << 18) | ((uint32_t)p << 9);

    int bestKey = -1, bestJ = 0;
    #pragma unroll
    for (int k = 0; k < 8; ++k) {
      const int j = lane + (k << 6);
      const float dj = drp[j];
      if (slab[j] != la && dj > dap && dj < hi) {
        const int key = (int)(threefry_bits(base + (uint32_t)j) >> 9);
        if (key > bestKey) { bestKey = key; bestJ = j; }
      }
    }
    #pragma unroll
    for (int m = 32; m; m >>= 1) {
      const int ok = __shfl_xor(bestKey, m);
      const int oj = __shfl_xor(bestJ, m);
      if (ok > bestKey || (ok == bestKey && oj < bestJ)) { bestKey = ok; bestJ = oj; }
    }
    if (lane == 0 && bestKey >= 0) {
      const float term = (dap - drp[bestJ]) + MARGIN_F;
      lsum += (unsigned long long)((double)term * FIX_SCALE + 0.5);
      lcnt += 1ull;
    }
  }

  // ---- Block reduce (integer, fixed order) -> private slot, no atomics ----
  if (lane == 0) { wsum[wave] = lsum; wcnt[wave] = lcnt; }
  __syncthreads();
  if (t == 0) {
    unsigned long long s = 0ull, c = 0ull;
    #pragma unroll
    for (int w = 0; w < 8; ++w) { s += wsum[w]; c += wcnt[w]; }
    part[2 * blockIdx.x]     = s;
    part[2 * blockIdx.x + 1] = c;
  }
}

__global__ __launch_bounds__(64) void triplet_finalize(
    const unsigned long long* __restrict__ part,
    float* __restrict__ out)
{
  const int lane = threadIdx.x;
  unsigned long long s = 0ull, c = 0ull;
  #pragma unroll
  for (int k = 0; k < NBLK / 64; ++k) {
    const int b = lane + (k << 6);
    s += part[2 * b];
    c += part[2 * b + 1];
  }
  #pragma unroll
  for (int m = 32; m; m >>= 1) {
    s += __shfl_xor(s, m);
    c += __shfl_xor(c, m);
  }
  if (lane == 0) {
    const double sd = (double)s / FIX_SCALE;
    const double cd = c ? (double)c : 1.0;
    out[0] = (float)(sd / cd);
  }
}

extern "C" void kernel_launch(void* const* d_in, const int* in_sizes, int n_in,
                              void* d_out, int out_size, void* d_ws, size_t ws_size,
                              hipStream_t stream) {
  const float* emb  = (const float*)d_in[0];
  const int* labels = (const int*)d_in[1];
  float* out        = (float*)d_out;
  unsigned long long* part = (unsigned long long*)d_ws;  // 256 * 16 B = 4 KB

  triplet_main<<<dim3(NBLK), dim3(512), 0, stream>>>(emb, labels, part);
  triplet_finalize<<<dim3(1), dim3(64), 0, stream>>>(part, out);
}